// Round 11
// baseline (265.462 us; speedup 1.0000x reference)
//
#include <hip/hip_runtime.h>

#define B_ 4096
#define T_ 256
#define I_ 16
#define H_ 32

typedef _Float16 f16x4 __attribute__((ext_vector_type(4)));
typedef _Float16 f16x8 __attribute__((ext_vector_type(8)));
typedef float    f32x4 __attribute__((ext_vector_type(4)));

#define MSIG  (-1.442695041f)
#define MTANH (-2.885390082f)

// Swapped-operand MFMA LSTM, 16x16x32_f16 ONLY (m89/m101-verified shape).
//   gates^T[128 rows][16 elems] = [Wih|0 pad K32] @ [x_t;*] + Whh(K32) @ h
// C/D (m89): lane holds col N = l&15 (elem), rows M = (l>>4)*4+reg.
// x-part zero-padding via A: lanes lg>=2 hold ZERO Wih fragments (loop-
// invariant), so B's k>=16 garbage contributes nothing.
// Block = 2 waves; wave w owns hidden cols j in [16w,16w+16) of all 4 gates.
// h exchanged via double-buffered LDS (f16, padded stride 40), 1 barrier/step.
__global__ __launch_bounds__(128, 1)
void lstm_mfma2(const float* __restrict__ x,
                const float* __restrict__ Wih,
                const float* __restrict__ Whh,
                const float* __restrict__ bih,
                const float* __restrict__ bhh,
                const float* __restrict__ Wfc,
                const float* __restrict__ bfc,
                float* __restrict__ out)
{
    __shared__ __align__(16) _Float16 hbuf[2][16][40];  // [dbuf][elem][j pad 32->40]

    const int tid  = threadIdx.x;
    const int wave = tid >> 6;
    const int l    = tid & 63;
    const int lr   = l & 15;   // elem (B n / C col); W row-within-tile (A m)
    const int lg   = l >> 4;   // k-block; C row-group
    const int b0   = blockIdx.x * 16;

    // ---- static A-fragments (weights) + folded bias constants ----
    f16x8 whhA[4];     // gate q: A[m=lr][k=lg*8+j] of Whh tile rows q*32+16w..
    f16x8 wihA[4];     // same, Wih zero-padded to K=32: lanes lg>=2 all-zero
    float mb[4][4];
#pragma unroll
    for (int q = 0; q < 4; ++q) {
        const int rowA = q * 32 + wave * 16 + lr;
        const float* ph = Whh + rowA * H_ + lg * 8;
#pragma unroll
        for (int k = 0; k < 8; ++k) whhA[q][k] = (_Float16)ph[k];
        const float* pi = Wih + rowA * I_ + (lg & 1) * 8;
#pragma unroll
        for (int k = 0; k < 8; ++k)
            wihA[q][k] = (lg < 2) ? (_Float16)pi[k] : (_Float16)0.0f;
        const float m = (q == 2) ? MTANH : MSIG;
#pragma unroll
        for (int r = 0; r < 4; ++r) {
            const int rowC = q * 32 + wave * 16 + lg * 4 + r;
            mb[q][r] = m * (bih[rowC] + bhh[rowC]);
        }
    }

    // zero h double-buffer (t=0 reads buf 0)
    for (int i = tid; i < 2 * 16 * 40; i += 128)
        ((_Float16*)hbuf)[i] = (_Float16)0.0f;
    __syncthreads();

    float c0 = 0.f, c1 = 0.f, c2 = 0.f, c3 = 0.f;

    // x stream: lane holds x[b0+lr][t][(lg&1)*8 .. +8] as f16x8.
    // lanes lg>=2 alias lg&1's addresses (same cachelines; A is zero there).
    const float* xbase = x + (size_t)(b0 + lr) * (T_ * I_) + (lg & 1) * 8;
    f16x8 xf[8];
#pragma unroll
    for (int k = 0; k < 8; ++k) {
        const float4 u0 = *reinterpret_cast<const float4*>(xbase + k * I_);
        const float4 u1 = *reinterpret_cast<const float4*>(xbase + k * I_ + 4);
        f16x8 w;
        w[0] = (_Float16)u0.x; w[1] = (_Float16)u0.y;
        w[2] = (_Float16)u0.z; w[3] = (_Float16)u0.w;
        w[4] = (_Float16)u1.x; w[5] = (_Float16)u1.y;
        w[6] = (_Float16)u1.z; w[7] = (_Float16)u1.w;
        xf[k] = w;
    }

    const f32x4 zf = {0.f, 0.f, 0.f, 0.f};

    for (int tb = 0; tb < 32; ++tb) {          // 32 chunks x 8 steps
#pragma unroll
        for (int tt = 0; tt < 8; ++tt) {       // global t = tb*8+tt
            const f16x8 xB = xf[tt];
            if (tb < 31) {
                const float* nx = xbase + ((tb + 1) * 8 + tt) * I_;
                const float4 u0 = *reinterpret_cast<const float4*>(nx);
                const float4 u1 = *reinterpret_cast<const float4*>(nx + 4);
                f16x8 w;
                w[0] = (_Float16)u0.x; w[1] = (_Float16)u0.y;
                w[2] = (_Float16)u0.z; w[3] = (_Float16)u0.w;
                w[4] = (_Float16)u1.x; w[5] = (_Float16)u1.y;
                w[6] = (_Float16)u1.z; w[7] = (_Float16)u1.w;
                xf[tt] = w;
            }

            const f16x8 hB = *reinterpret_cast<const f16x8*>(&hbuf[tt & 1][lr][lg * 8]);

            // x-part (zero-padded K=32) then h-part (K=32), both verified shape
            f32x4 a0 = __builtin_amdgcn_mfma_f32_16x16x32_f16(wihA[0], xB, zf, 0, 0, 0);
            f32x4 a1 = __builtin_amdgcn_mfma_f32_16x16x32_f16(wihA[1], xB, zf, 0, 0, 0);
            f32x4 a2 = __builtin_amdgcn_mfma_f32_16x16x32_f16(wihA[2], xB, zf, 0, 0, 0);
            f32x4 a3 = __builtin_amdgcn_mfma_f32_16x16x32_f16(wihA[3], xB, zf, 0, 0, 0);
            a0 = __builtin_amdgcn_mfma_f32_16x16x32_f16(whhA[0], hB, a0, 0, 0, 0);
            a1 = __builtin_amdgcn_mfma_f32_16x16x32_f16(whhA[1], hB, a1, 0, 0, 0);
            a2 = __builtin_amdgcn_mfma_f32_16x16x32_f16(whhA[2], hB, a2, 0, 0, 0);
            a3 = __builtin_amdgcn_mfma_f32_16x16x32_f16(whhA[3], hB, a3, 0, 0, 0);

            // activations: i=sigm(a0), f=sigm(a1), g=tanh(a2), o=sigm(a3); bias folded
            float si[4], sf[4], tg[4], so[4];
#pragma unroll
            for (int r = 0; r < 4; ++r) {
                si[r] = __builtin_amdgcn_rcpf(1.0f + __builtin_amdgcn_exp2f(__fmaf_rn(MSIG,  a0[r], mb[0][r])));
                sf[r] = __builtin_amdgcn_rcpf(1.0f + __builtin_amdgcn_exp2f(__fmaf_rn(MSIG,  a1[r], mb[1][r])));
                tg[r] = __fmaf_rn(2.0f, __builtin_amdgcn_rcpf(1.0f + __builtin_amdgcn_exp2f(__fmaf_rn(MTANH, a2[r], mb[2][r]))), -1.0f);
                so[r] = __builtin_amdgcn_rcpf(1.0f + __builtin_amdgcn_exp2f(__fmaf_rn(MSIG,  a3[r], mb[3][r])));
            }

            c0 = __fmaf_rn(sf[0], c0, si[0] * tg[0]);
            c1 = __fmaf_rn(sf[1], c1, si[1] * tg[1]);
            c2 = __fmaf_rn(sf[2], c2, si[2] * tg[2]);
            c3 = __fmaf_rn(sf[3], c3, si[3] * tg[3]);
            const float t0 = __fmaf_rn(2.0f, __builtin_amdgcn_rcpf(1.0f + __builtin_amdgcn_exp2f(MTANH * c0)), -1.0f);
            const float t1 = __fmaf_rn(2.0f, __builtin_amdgcn_rcpf(1.0f + __builtin_amdgcn_exp2f(MTANH * c1)), -1.0f);
            const float t2 = __fmaf_rn(2.0f, __builtin_amdgcn_rcpf(1.0f + __builtin_amdgcn_exp2f(MTANH * c2)), -1.0f);
            const float t3 = __fmaf_rn(2.0f, __builtin_amdgcn_rcpf(1.0f + __builtin_amdgcn_exp2f(MTANH * c3)), -1.0f);
            const float h0 = so[0] * t0, h1 = so[1] * t1, h2 = so[2] * t2, h3 = so[3] * t3;

            // write h (elem=lr, j = 16*wave + lg*4 + r) into next buffer
            f16x4 hv;
            hv[0] = (_Float16)h0; hv[1] = (_Float16)h1;
            hv[2] = (_Float16)h2; hv[3] = (_Float16)h3;
            *reinterpret_cast<f16x4*>(&hbuf[(tt + 1) & 1][lr][wave * 16 + lg * 4]) = hv;

            __syncthreads();
        }
    }

    // ---- FC epilogue: out[b0+e] = h_last[e][:] . Wfc + bfc ----
    // last write went to buf (256&1)=0
    if (tid < 64) {
        const f16x8 hL = *reinterpret_cast<const f16x8*>(&hbuf[0][lr][lg * 8]);
        const float* pw = Wfc + lg * 8;
        float p = 0.f;
#pragma unroll
        for (int k = 0; k < 8; ++k) p += (float)hL[k] * pw[k];
        p += __shfl_xor(p, 16, 64);
        p += __shfl_xor(p, 32, 64);
        if (lg == 0) out[b0 + lr] = p + bfc[0];
    }
}

extern "C" void kernel_launch(void* const* d_in, const int* in_sizes, int n_in,
                              void* d_out, int out_size, void* d_ws, size_t ws_size,
                              hipStream_t stream) {
    const float* x   = (const float*)d_in[0];
    const float* Wih = (const float*)d_in[1];
    const float* Whh = (const float*)d_in[2];
    const float* bih = (const float*)d_in[3];
    const float* bhh = (const float*)d_in[4];
    const float* Wfc = (const float*)d_in[5];
    const float* bfc = (const float*)d_in[6];
    float* out = (float*)d_out;

    dim3 grid(B_ / 16);
    dim3 block(128);
    hipLaunchKernelGGL(lstm_mfma2, grid, block, 0, stream,
                       x, Wih, Whh, bih, bhh, Wfc, bfc, out);
}